// Round 10
// baseline (237.363 us; speedup 1.0000x reference)
//
#include <hip/hip_runtime.h>
#include <hip/hip_bf16.h>
#include <stdint.h>

#define T_TOK 2048
#define HID   1024
#define FFN_  2048
#define NEXP  8
#define NPAIR 4096   // T_TOK * top_k(2)
#define MAXTILE 40   // sum over experts of ceil(cnt/128) <= 32+8
#define EXPELEM ((size_t)HID * FFN_)   // elems per expert matrix (2M)

typedef __bf16 bf16;
typedef __bf16 bf16x8 __attribute__((ext_vector_type(8)));
typedef __bf16 bf16x4 __attribute__((ext_vector_type(4)));
typedef float  f32x4  __attribute__((ext_vector_type(4)));
typedef unsigned int u32;

// ---- workspace layout (bytes) ----
#define OFF_EXP   0
#define OFF_NT    64
#define OFF_TTE   128
#define OFF_TTM   512
#define OFF_TOK   1024
#define OFF_WGT   (OFF_TOK + 16384)
#define OFF_XG    65536
#define OFF_H1    (OFF_XG + (size_t)NPAIR*HID*2)
#define OFF_WT    (OFF_H1 + (size_t)NPAIR*FFN_*2)

__device__ __forceinline__ void gld16(const void* g, void* l) {
    __builtin_amdgcn_global_load_lds(
        (const __attribute__((address_space(1))) u32*)g,
        (__attribute__((address_space(3))) u32*)l, 16, 0, 0);
}

// ---------------- routing ----------------------------------------------------
__global__ void route_kernel(const uint32_t* __restrict__ te_raw,
                             const float* __restrict__ top_w,
                             int* __restrict__ expert_off,
                             int* __restrict__ ntile_g,
                             int* __restrict__ tte, int* __restrict__ ttm,
                             int* __restrict__ tok, float* __restrict__ wgt)
{
    __shared__ int counts[NEXP];
    __shared__ int offs[NEXP + 1];
    __shared__ int is64_s;
    int tid = threadIdx.x;
    int wv = tid >> 6, lane = tid & 63;
    if (tid == 0) {
        int z = 1;
        for (int i = 0; i < 64; ++i) if (te_raw[2*i + 1] != 0u) { z = 0; break; }
        is64_s = z;
    }
    __syncthreads();
    int is64 = is64_s;
    int cnt = 0;
    for (int base = 0; base < NPAIR; base += 64) {
        int p = base + lane;
        int eid = is64 ? (int)te_raw[2*p] : (int)te_raw[p];
        unsigned long long m = __ballot(eid == wv);
        cnt += __popcll(m);
    }
    if (lane == 0) counts[wv] = cnt;
    __syncthreads();
    if (tid == 0) {
        int s = 0;
        for (int e2 = 0; e2 < NEXP; ++e2) { offs[e2] = s; expert_off[e2] = s; s += counts[e2]; }
        offs[NEXP] = s; expert_off[NEXP] = s;
        int nt = 0;
        for (int e2 = 0; e2 < NEXP; ++e2)
            for (int m = offs[e2]; m < offs[e2 + 1]; m += 128) { tte[nt] = e2; ttm[nt] = m; ++nt; }
        *ntile_g = nt;
    }
    __syncthreads();
    int off = offs[wv];
    for (int base = 0; base < NPAIR; base += 64) {
        int p = base + lane;
        int eid = is64 ? (int)te_raw[2*p] : (int)te_raw[p];
        unsigned long long m = __ballot(eid == wv);
        if (eid == wv) {
            int pre = __popcll(m & ((1ull << lane) - 1ull));
            int s = off + pre;
            tok[s] = p >> 1;
            wgt[s] = top_w[p];
        }
        off += __popcll(m);
    }
}

// ---------------- gather -----------------------------------------------------
__global__ void gather_kernel(const float* __restrict__ x,
                              const int* __restrict__ tok,
                              bf16* __restrict__ Xg)
{
    int p = blockIdx.x;
    int t = tok[p];
    const float4* src = (const float4*)(x + (size_t)t * HID);
    float4 v = src[threadIdx.x];
    bf16x4 o;
    o[0] = (bf16)v.x; o[1] = (bf16)v.y; o[2] = (bf16)v.z; o[3] = (bf16)v.w;
    *(bf16x4*)(Xg + (size_t)p * HID + threadIdx.x * 4) = o;
}

// ---------------- fused phase: GEMM blocks + transpose blocks ----------------
// bid < ngemm            -> GEMM (KIND 0: upgate dual-matrix; KIND 1: down)
// ngemm <= bid           -> 64x64 transpose+convert tile (v2 swizzle)
template<int KIND>
__global__ void __launch_bounds__(256)
fused_phase(const bf16* __restrict__ Ain,      // Xg (ug) or H1 (down)
            const bf16* __restrict__ wTa,      // wuT (ug) or wdT (down)
            const bf16* __restrict__ wTb,      // wgT (ug); unused for down
            const int* __restrict__ expert_off, const int* __restrict__ ntile_g,
            const int* __restrict__ tte, const int* __restrict__ ttm,
            int eb, int gcnt,
            bf16* __restrict__ H1out,
            const int* __restrict__ tok, const float* __restrict__ wgt,
            float* __restrict__ out,
            int ngemm, int nN,
            const float* __restrict__ tin1, bf16* __restrict__ tout1,
            const float* __restrict__ tin2, bf16* __restrict__ tout2,
            int tnz1, int tR, int tC, int ntrxy)
{
    __shared__ char lds[32768];
    __shared__ float wgt_s[128];
    __shared__ int   tok_s[128];
    int bid = blockIdx.x;
    int tid = threadIdx.x;

    if (bid >= ngemm) {
        // ---------------- transpose path ----------------
        int tb = bid - ngemm;
        int z = tb / ntrxy, rem = tb - z * ntrxy;
        int nbx = tC >> 6;
        int by = rem / nbx, bx = rem - by * nbx;
        const float* in; bf16* o; int e2;
        if (z < tnz1) { in = tin1; o = tout1; e2 = z; }
        else          { in = tin2; o = tout2; e2 = z - tnz1; }
        size_t esz = (size_t)tR * tC;
        in += (size_t)e2 * esz; o += (size_t)e2 * esz;
        u32* tile = (u32*)lds;                 // 8 KB of the 32 KB block
        int r0 = by * 64, c0 = bx * 64;
        int rr = tid >> 4, cq = tid & 15;
        #pragma unroll
        for (int it = 0; it < 4; ++it) {
            int k = rr + it * 16;
            float4 v = *(const float4*)(in + (size_t)(r0 + k) * tC + c0 + cq * 4);
            union { bf16 h[2]; u32 w; } a, b;
            a.h[0] = (bf16)v.x; a.h[1] = (bf16)v.y;
            b.h[0] = (bf16)v.z; b.h[1] = (bf16)v.w;
            int fp0 = cq * 2;
            tile[k * 32 + (fp0       ^ (k & 31))] = a.w;
            tile[k * 32 + ((fp0 + 1) ^ (k & 31))] = b.w;
        }
        __syncthreads();
        int kc = tid & 7, fp = tid >> 3;
        u32 rbuf[8];
        #pragma unroll
        for (int j = 0; j < 8; ++j) { int k = kc * 8 + j; rbuf[j] = tile[k * 32 + (fp ^ (k & 31))]; }
        union { bf16 h[8]; } lo2, hi2;
        #pragma unroll
        for (int j = 0; j < 8; ++j) {
            lo2.h[j] = ((bf16*)&rbuf[j])[0];
            hi2.h[j] = ((bf16*)&rbuf[j])[1];
        }
        size_t obase = (size_t)(c0 + 2 * fp) * tR + r0 + kc * 8;
        *(bf16x8*)(o + obase)      = *(bf16x8*)&lo2;
        *(bf16x8*)(o + obase + tR) = *(bf16x8*)&hi2;
        return;
    }

    // ---------------- GEMM path (R6-verified structure) ----------------
    int ty = bid / nN, bn = bid - ty * nN;
    if (ty >= *ntile_g) return;
    int e = tte[ty];
    if (e < eb || e >= eb + gcnt) return;
    int m0 = ttm[ty];
    int p1 = expert_off[e + 1];
    int n0 = bn * 64;
    constexpr int KDIM = (KIND == 0) ? HID : FFN_;
    bf16* As = (bf16*)lds;                 // 16 KB
    bf16* B0 = (bf16*)(lds + 16384);       // 8 KB
    bf16* B1 = (bf16*)(lds + 24576);       // 8 KB (ug only)
    int lane = tid & 63, wvi = tid >> 6;
    int wm = wvi >> 1, wn = wvi & 1;
    int l16 = lane & 15, lhi = lane >> 4;

    if (KIND == 1) {
        if (tid < 128) {
            int r = m0 + tid;
            if (r < p1) { wgt_s[tid] = wgt[r]; tok_s[tid] = tok[r]; }
            else        { wgt_s[tid] = 0.f;    tok_s[tid] = 0; }
        }
    }
    f32x4 accA[4][2] = {};
    f32x4 accB[4][2] = {};

    const bf16* aptr[4]; u32 alds[4];
    #pragma unroll
    for (int c = 0; c < 4; ++c) {
        int g = c * 256 + tid;
        int r = g >> 3, pos = g & 7;
        int gr = m0 + r; if (gr >= p1) gr = p1 - 1;
        int gsrc = pos ^ (r & 7);
        aptr[c] = Ain + (size_t)gr * KDIM + gsrc * 8;
        alds[c] = g * 16;
    }
    const bf16* wa = wTa + (size_t)(e - eb) * EXPELEM;
    const bf16* wb = wTb + (size_t)(e - eb) * EXPELEM;
    const bf16* bptrA[2]; const bf16* bptrB[2]; u32 blds[2];
    #pragma unroll
    for (int c = 0; c < 2; ++c) {
        int g = c * 256 + tid;
        int f = g >> 3, pos = g & 7;
        int gsrc = pos ^ (f & 7);
        size_t so = (size_t)(n0 + f) * KDIM + gsrc * 8;
        bptrA[c] = wa + so;
        bptrB[c] = wb + so;
        blds[c] = g * 16;
    }
    u32 aro[2][4], bro[2][2];
    #pragma unroll
    for (int ks = 0; ks < 2; ++ks) {
        #pragma unroll
        for (int fm = 0; fm < 4; ++fm) {
            int r = wm * 64 + fm * 16 + l16;
            aro[ks][fm] = r * 128 + ((u32)((ks * 4 + lhi) ^ (r & 7))) * 16;
        }
        #pragma unroll
        for (int fn = 0; fn < 2; ++fn) {
            int fr = wn * 32 + fn * 16 + l16;
            bro[ks][fn] = fr * 128 + ((u32)((ks * 4 + lhi) ^ (fr & 7))) * 16;
        }
    }

    for (int t = 0; t < KDIM / 64; ++t) {
        #pragma unroll
        for (int c = 0; c < 4; ++c) { gld16(aptr[c], (char*)As + alds[c]); aptr[c] += 64; }
        #pragma unroll
        for (int c = 0; c < 2; ++c) {
            gld16(bptrA[c], (char*)B0 + blds[c]); bptrA[c] += 64;
            if (KIND == 0) { gld16(bptrB[c], (char*)B1 + blds[c]); bptrB[c] += 64; }
        }
        __syncthreads();
        #pragma unroll
        for (int ks = 0; ks < 2; ++ks) {
            bf16x8 af[4];
            #pragma unroll
            for (int fm = 0; fm < 4; ++fm)
                af[fm] = *(const bf16x8*)((char*)As + aro[ks][fm]);
            #pragma unroll
            for (int fn = 0; fn < 2; ++fn) {
                bf16x8 ba = *(const bf16x8*)((char*)B0 + bro[ks][fn]);
                #pragma unroll
                for (int fm = 0; fm < 4; ++fm)
                    accA[fm][fn] = __builtin_amdgcn_mfma_f32_16x16x32_bf16(af[fm], ba, accA[fm][fn], 0, 0, 0);
                if (KIND == 0) {
                    bf16x8 bb = *(const bf16x8*)((char*)B1 + bro[ks][fn]);
                    #pragma unroll
                    for (int fm = 0; fm < 4; ++fm)
                        accB[fm][fn] = __builtin_amdgcn_mfma_f32_16x16x32_bf16(af[fm], bb, accB[fm][fn], 0, 0, 0);
                }
            }
        }
        __syncthreads();
    }
    #pragma unroll
    for (int fm = 0; fm < 4; ++fm)
    #pragma unroll
    for (int fn = 0; fn < 2; ++fn)
    #pragma unroll
    for (int rg = 0; rg < 4; ++rg) {
        int rl = wm * 64 + fm * 16 + lhi * 4 + rg;
        int r = m0 + rl;
        if (r < p1) {
            int fc = n0 + wn * 32 + fn * 16 + l16;
            if (KIND == 0) {
                float u = accA[fm][fn][rg], g = accB[fm][fn][rg];
                float h = (u / (1.f + __expf(-u))) * g;
                H1out[(size_t)r * FFN_ + fc] = (bf16)h;
            } else {
                float v = accA[fm][fn][rg] * wgt_s[rl];
                atomicAdd(out + (size_t)tok_s[rl] * HID + fc, v);
            }
        }
    }
}

extern "C" void kernel_launch(void* const* d_in, const int* in_sizes, int n_in,
                              void* d_out, int out_size, void* d_ws, size_t ws_size,
                              hipStream_t stream)
{
    const float*    x      = (const float*)d_in[0];
    const float*    top_w  = (const float*)d_in[2];
    const uint32_t* te     = (const uint32_t*)d_in[3];
    const float*    w_up   = (const float*)d_in[4];
    const float*    w_gate = (const float*)d_in[5];
    const float*    w_down = (const float*)d_in[6];
    float* out = (float*)d_out;
    char*  ws  = (char*)d_ws;

    int*   expert_off = (int*)(ws + OFF_EXP);
    int*   ntile_g    = (int*)(ws + OFF_NT);
    int*   tte        = (int*)(ws + OFF_TTE);
    int*   ttm        = (int*)(ws + OFF_TTM);
    int*   tok        = (int*)(ws + OFF_TOK);
    float* wgt        = (float*)(ws + OFF_WGT);
    bf16*  Xg         = (bf16*)(ws + OFF_XG);
    bf16*  H1         = (bf16*)(ws + OFF_H1);
    bf16*  WT         = (bf16*)(ws + OFF_WT);

    const int NG_UG = 32 * MAXTILE;   // 1280
    const int NG_DN = 16 * MAXTILE;   // 640
    const int TR_UG = 8 * 512;        // 4 up + 4 gate experts, 512 tiles each
    const int TR_DN = 4 * 512;

    hipMemsetAsync(out, 0, (size_t)out_size * sizeof(float), stream);
    hipLaunchKernelGGL(route_kernel, dim3(1), dim3(512), 0, stream,
                       te, top_w, expert_off, ntile_g, tte, ttm, tok, wgt);
    hipLaunchKernelGGL(gather_kernel, dim3(NPAIR), dim3(256), 0, stream,
                       x, tok, Xg);

    bool pipe = ws_size >= (size_t)OFF_WT + 24 * EXPELEM * sizeof(bf16);
    if (pipe) {
        bf16* bu0 = WT;                       // [wu x4 | wg x4] 32 MB
        bf16* bu1 = WT + 8 * EXPELEM;
        bf16* bd0 = WT + 16 * EXPELEM;        // [wd x4] 16 MB
        bf16* bd1 = WT + 20 * EXPELEM;
        // L1: transpose ug grp0
        hipLaunchKernelGGL((fused_phase<0>), dim3(TR_UG), dim3(256), 0, stream,
            Xg, bu0, bu0, expert_off, ntile_g, tte, ttm, 0, 0, H1, tok, wgt, out,
            0, 32, w_up, bu0, w_gate, bu0 + 4 * EXPELEM, 4, HID, FFN_, 512);
        // L2: gemm ug grp0 || transpose ug grp1
        hipLaunchKernelGGL((fused_phase<0>), dim3(NG_UG + TR_UG), dim3(256), 0, stream,
            Xg, bu0, bu0 + 4 * EXPELEM, expert_off, ntile_g, tte, ttm, 0, 4, H1, tok, wgt, out,
            NG_UG, 32, w_up + 4 * EXPELEM, bu1, w_gate + 4 * EXPELEM, bu1 + 4 * EXPELEM, 4, HID, FFN_, 512);
        // L3: gemm ug grp1 || transpose down grp0
        hipLaunchKernelGGL((fused_phase<0>), dim3(NG_UG + TR_DN), dim3(256), 0, stream,
            Xg, bu1, bu1 + 4 * EXPELEM, expert_off, ntile_g, tte, ttm, 4, 4, H1, tok, wgt, out,
            NG_UG, 32, w_down, bd0, w_down, bd0, 4, FFN_, HID, 512);
        // L4: gemm down grp0 || transpose down grp1
        hipLaunchKernelGGL((fused_phase<1>), dim3(NG_DN + TR_DN), dim3(256), 0, stream,
            H1, bd0, bd0, expert_off, ntile_g, tte, ttm, 0, 4, H1, tok, wgt, out,
            NG_DN, 16, w_down + 4 * EXPELEM, bd1, w_down + 4 * EXPELEM, bd1, 4, FFN_, HID, 512);
        // L5: gemm down grp1
        hipLaunchKernelGGL((fused_phase<1>), dim3(NG_DN), dim3(256), 0, stream,
            H1, bd1, bd1, expert_off, ntile_g, tte, ttm, 4, 4, H1, tok, wgt, out,
            NG_DN, 16, w_down, bd0, w_down, bd0, 0, FFN_, HID, 512);
    } else {
        // serial fallback (R9 structure): per-group transpose-only then gemm-only
        size_t wtcap = ws_size > (size_t)OFF_WT ? ws_size - (size_t)OFF_WT : 0;
        size_t perexpB = EXPELEM * sizeof(bf16);
        int g1 = (int)(wtcap / (2 * perexpB));
        g1 = g1 >= 4 ? 4 : g1 >= 2 ? 2 : 1;
        int g2 = (int)(wtcap / perexpB);
        g2 = g2 >= 4 ? 4 : g2 >= 2 ? 2 : 1;
        for (int eb = 0; eb < NEXP; eb += g1) {
            bf16* wuT = WT;
            bf16* wgT = WT + (size_t)g1 * EXPELEM;
            hipLaunchKernelGGL((fused_phase<0>), dim3(2 * g1 * 512), dim3(256), 0, stream,
                Xg, wuT, wgT, expert_off, ntile_g, tte, ttm, 0, 0, H1, tok, wgt, out,
                0, 32, w_up + (size_t)eb * EXPELEM, wuT, w_gate + (size_t)eb * EXPELEM, wgT,
                g1, HID, FFN_, 512);
            hipLaunchKernelGGL((fused_phase<0>), dim3(NG_UG), dim3(256), 0, stream,
                Xg, wuT, wgT, expert_off, ntile_g, tte, ttm, eb, g1, H1, tok, wgt, out,
                NG_UG, 32, w_up, wuT, w_up, wuT, 0, HID, FFN_, 512);
        }
        for (int eb = 0; eb < NEXP; eb += g2) {
            hipLaunchKernelGGL((fused_phase<0>), dim3(g2 * 512), dim3(256), 0, stream,
                Xg, WT, WT, expert_off, ntile_g, tte, ttm, 0, 0, H1, tok, wgt, out,
                0, 32, w_down + (size_t)eb * EXPELEM, WT, w_down + (size_t)eb * EXPELEM, WT,
                g2, FFN_, HID, 512);
            hipLaunchKernelGGL((fused_phase<1>), dim3(NG_DN), dim3(256), 0, stream,
                H1, WT, WT, expert_off, ntile_g, tte, ttm, eb, g2, H1, tok, wgt, out,
                NG_DN, 16, w_down, WT, w_down, WT, 0, FFN_, HID, 512);
        }
    }
}

// Round 11
// 193.420 us; speedup vs baseline: 1.2272x; 1.2272x over previous
//
#include <hip/hip_runtime.h>
#include <hip/hip_bf16.h>
#include <stdint.h>

#define T_TOK 2048
#define HID   1024
#define FFN_  2048
#define NEXP  8
#define NPAIR 4096   // T_TOK * top_k(2)
#define MAXTILE 40   // sum over experts of ceil(cnt/128) <= 32+8
#define EXPELEM ((size_t)HID * FFN_)

typedef __bf16 bf16;
typedef __bf16 bf16x8 __attribute__((ext_vector_type(8)));
typedef __bf16 bf16x4 __attribute__((ext_vector_type(4)));
typedef float  f32x4  __attribute__((ext_vector_type(4)));
typedef unsigned int u32;

// ---- workspace layout (bytes) ----
#define OFF_EXP   0
#define OFF_NT    64
#define OFF_TTE   128
#define OFF_TTM   512
#define OFF_TOK   1024
#define OFF_WGT   (OFF_TOK + 16384)
#define OFF_XG    65536
#define OFF_H1    (OFF_XG + (size_t)NPAIR*HID*2)
#define OFF_WT    (OFF_H1 + (size_t)NPAIR*FFN_*2)

__device__ __forceinline__ void gld16(const void* g, void* l) {
    __builtin_amdgcn_global_load_lds(
        (const __attribute__((address_space(1))) u32*)g,
        (__attribute__((address_space(3))) u32*)l, 16, 0, 0);
}

// ---------------- routing: stable counting sort of pairs by expert ----------
__global__ void route_kernel(const uint32_t* __restrict__ te_raw,
                             const float* __restrict__ top_w,
                             int* __restrict__ expert_off,
                             int* __restrict__ ntile_g,
                             int* __restrict__ tte, int* __restrict__ ttm,
                             int* __restrict__ tok, float* __restrict__ wgt)
{
    __shared__ int counts[NEXP];
    __shared__ int offs[NEXP + 1];
    __shared__ int is64_s;
    int tid = threadIdx.x;
    int wv = tid >> 6, lane = tid & 63;
    if (tid == 0) {
        int z = 1;
        for (int i = 0; i < 64; ++i) if (te_raw[2*i + 1] != 0u) { z = 0; break; }
        is64_s = z;
    }
    __syncthreads();
    int is64 = is64_s;
    int cnt = 0;
    for (int base = 0; base < NPAIR; base += 64) {
        int p = base + lane;
        int eid = is64 ? (int)te_raw[2*p] : (int)te_raw[p];
        unsigned long long m = __ballot(eid == wv);
        cnt += __popcll(m);
    }
    if (lane == 0) counts[wv] = cnt;
    __syncthreads();
    if (tid == 0) {
        int s = 0;
        for (int e2 = 0; e2 < NEXP; ++e2) { offs[e2] = s; expert_off[e2] = s; s += counts[e2]; }
        offs[NEXP] = s; expert_off[NEXP] = s;
        int nt = 0;
        for (int e2 = 0; e2 < NEXP; ++e2)
            for (int m = offs[e2]; m < offs[e2 + 1]; m += 128) { tte[nt] = e2; ttm[nt] = m; ++nt; }
        *ntile_g = nt;
    }
    __syncthreads();
    int off = offs[wv];
    for (int base = 0; base < NPAIR; base += 64) {
        int p = base + lane;
        int eid = is64 ? (int)te_raw[2*p] : (int)te_raw[p];
        unsigned long long m = __ballot(eid == wv);
        if (eid == wv) {
            int pre = __popcll(m & ((1ull << lane) - 1ull));
            int s = off + pre;
            tok[s] = p >> 1;
            wgt[s] = top_w[p];
        }
        off += __popcll(m);
    }
}

// ---------------- gather x rows -> bf16 -------------------------------------
__global__ void gather_kernel(const float* __restrict__ x,
                              const int* __restrict__ tok,
                              bf16* __restrict__ Xg)
{
    int p = blockIdx.x;
    int t = tok[p];
    const float4* src = (const float4*)(x + (size_t)t * HID);
    float4 v = src[threadIdx.x];
    bf16x4 o;
    o[0] = (bf16)v.x; o[1] = (bf16)v.y; o[2] = (bf16)v.z; o[3] = (bf16)v.w;
    *(bf16x4*)(Xg + (size_t)p * HID + threadIdx.x * 4) = o;
}

// --------- transpose v3: f32 [R][C] -> tile-sequential pre-swizzled images --
// Output: per 64(k=R-dim)x64(n=C-dim) tile, the exact 8 KB LDS byte image the
// GEMM's gld16 staging consumes: granule g (0..511) = W^T[f=g>>3]
// [k8=((g&7)^(f&7))*8 ..+8], stored at tile_base + g*16B, tiles ordered
// tileidx = nt*(R/64) + kt. Global writes fully contiguous.
// Two source tensors per launch (z < nz1 -> in1/out1, else in2/out2).
__global__ void __launch_bounds__(256)
transpose_v3(const float* __restrict__ in1, bf16* __restrict__ out1,
             const float* __restrict__ in2, bf16* __restrict__ out2,
             int nz1, int R, int C)
{
    __shared__ u32 tile32[64 * 32];  // 8 KB  [k][fpair], swizzle fp ^ (k&31)
    int z = blockIdx.z;
    const float* in = (z < nz1) ? in1 : in2;
    bf16* o         = (z < nz1) ? out1 : out2;
    int e = (z < nz1) ? z : z - nz1;
    in += (size_t)e * R * C;
    o  += (size_t)e * R * C;
    int kt = blockIdx.x, nt = blockIdx.y;
    int k0 = kt * 64, c0 = nt * 64;
    int tid = threadIdx.x;
    int rr = tid >> 4, cq = tid & 15;
    #pragma unroll
    for (int it = 0; it < 4; ++it) {
        int k = rr + it * 16;
        float4 v = *(const float4*)(in + (size_t)(k0 + k) * C + c0 + cq * 4);
        union { bf16 h[2]; u32 w; } a, b;
        a.h[0] = (bf16)v.x; a.h[1] = (bf16)v.y;
        b.h[0] = (bf16)v.z; b.h[1] = (bf16)v.w;
        int fp0 = cq * 2;
        tile32[k * 32 + (fp0       ^ (k & 31))] = a.w;
        tile32[k * 32 + ((fp0 + 1) ^ (k & 31))] = b.w;
    }
    __syncthreads();
    bf16* tbase = o + ((size_t)nt * (R >> 6) + kt) * 4096;
    #pragma unroll
    for (int c = 0; c < 2; ++c) {
        int g = c * 256 + tid;
        int f = g >> 3;
        int k8 = ((g & 7) ^ (f & 7)) * 8;
        union { bf16 h[8]; } pk;
        #pragma unroll
        for (int j = 0; j < 8; ++j) {
            u32 u = tile32[(k8 + j) * 32 + ((f >> 1) ^ ((k8 + j) & 31))];
            pk.h[j] = (f & 1) ? ((bf16*)&u)[1] : ((bf16*)&u)[0];
        }
        *(bf16x8*)(tbase + (size_t)g * 8) = *(bf16x8*)&pk;
    }
}

// ---------------- GEMM1: H1 = silu(Xg@Wu) * (Xg@Wg) per expert ---------------
// tile 128(M) x 64(N) x 2 matrices, BK=64, single-buffer, tile-table grid,
// hoisted invariants (R6-verified); B staged from tile-sequential images.
__global__ void __launch_bounds__(256)
moe_upgate(const bf16* __restrict__ Xg,
           const bf16* __restrict__ wuT, const bf16* __restrict__ wgT,
           const int* __restrict__ expert_off, const int* __restrict__ ntile_g,
           const int* __restrict__ tte, const int* __restrict__ ttm,
           int eb, int gcnt, bf16* __restrict__ H1)
{
    int ty = blockIdx.y;
    if (ty >= *ntile_g) return;
    int e = tte[ty];
    if (e < eb || e >= eb + gcnt) return;
    int m0 = ttm[ty];
    int p1 = expert_off[e + 1];
    int n0 = blockIdx.x * 64;
    __shared__ bf16 As [128 * 64];   // 16 KB
    __shared__ bf16 Bus[64 * 64];    // 8 KB
    __shared__ bf16 Bgs[64 * 64];    // 8 KB -> 32 KB total
    int tid = threadIdx.x, lane = tid & 63, wv = tid >> 6;
    int wm = wv >> 1, wn = wv & 1;
    int l16 = lane & 15, lhi = lane >> 4;
    f32x4 accU[4][2] = {};
    f32x4 accG[4][2] = {};

    const bf16* aptr[4]; u32 alds[4];
    #pragma unroll
    for (int c = 0; c < 4; ++c) {
        int g = c * 256 + tid;
        int r = g >> 3, pos = g & 7;
        int gr = m0 + r; if (gr >= p1) gr = p1 - 1;
        int gsrc = pos ^ (r & 7);
        aptr[c] = Xg + (size_t)gr * HID + gsrc * 8;
        alds[c] = g * 16;
    }
    // B: tile-sequential images, tileidx = (n0>>6)*(HID>>6) + t
    size_t tb0 = (size_t)(e - eb) * EXPELEM + (size_t)(n0 >> 6) * (HID >> 6) * 4096;
    const bf16* buptr[2]; const bf16* bgptr[2]; u32 blds[2];
    #pragma unroll
    for (int c = 0; c < 2; ++c) {
        int g = c * 256 + tid;
        buptr[c] = wuT + tb0 + (size_t)g * 8;
        bgptr[c] = wgT + tb0 + (size_t)g * 8;
        blds[c] = g * 16;
    }
    u32 aro[2][4], bro[2][2];
    #pragma unroll
    for (int ks = 0; ks < 2; ++ks) {
        #pragma unroll
        for (int fm = 0; fm < 4; ++fm) {
            int r = wm * 64 + fm * 16 + l16;
            aro[ks][fm] = r * 128 + ((u32)((ks * 4 + lhi) ^ (r & 7))) * 16;
        }
        #pragma unroll
        for (int fn = 0; fn < 2; ++fn) {
            int fr = wn * 32 + fn * 16 + l16;
            bro[ks][fn] = fr * 128 + ((u32)((ks * 4 + lhi) ^ (fr & 7))) * 16;
        }
    }

    for (int t = 0; t < HID / 64; ++t) {
        #pragma unroll
        for (int c = 0; c < 4; ++c) { gld16(aptr[c], (char*)As + alds[c]); aptr[c] += 64; }
        #pragma unroll
        for (int c = 0; c < 2; ++c) {
            gld16(buptr[c], (char*)Bus + blds[c]); buptr[c] += 4096;
            gld16(bgptr[c], (char*)Bgs + blds[c]); bgptr[c] += 4096;
        }
        __syncthreads();
        #pragma unroll
        for (int ks = 0; ks < 2; ++ks) {
            bf16x8 af[4];
            #pragma unroll
            for (int fm = 0; fm < 4; ++fm)
                af[fm] = *(const bf16x8*)((char*)As + aro[ks][fm]);
            #pragma unroll
            for (int fn = 0; fn < 2; ++fn) {
                bf16x8 bu = *(const bf16x8*)((char*)Bus + bro[ks][fn]);
                bf16x8 bg = *(const bf16x8*)((char*)Bgs + bro[ks][fn]);
                #pragma unroll
                for (int fm = 0; fm < 4; ++fm) {
                    accU[fm][fn] = __builtin_amdgcn_mfma_f32_16x16x32_bf16(af[fm], bu, accU[fm][fn], 0, 0, 0);
                    accG[fm][fn] = __builtin_amdgcn_mfma_f32_16x16x32_bf16(af[fm], bg, accG[fm][fn], 0, 0, 0);
                }
            }
        }
        __syncthreads();
    }
    #pragma unroll
    for (int fm = 0; fm < 4; ++fm)
    #pragma unroll
    for (int fn = 0; fn < 2; ++fn)
    #pragma unroll
    for (int rg = 0; rg < 4; ++rg) {
        int r = m0 + wm * 64 + fm * 16 + lhi * 4 + rg;
        if (r < p1) {
            float u = accU[fm][fn][rg], g = accG[fm][fn][rg];
            float h = (u / (1.f + __expf(-u))) * g;
            int fc = n0 + wn * 32 + fn * 16 + l16;
            H1[(size_t)r * FFN_ + fc] = (bf16)h;
        }
    }
}

// ---------------- GEMM2: out += (H1 @ Wdown) * wgt (atomic, 2 adds/elem) ----
__global__ void __launch_bounds__(256)
moe_down(const bf16* __restrict__ H1, const bf16* __restrict__ wdT,
         const int* __restrict__ expert_off, const int* __restrict__ ntile_g,
         const int* __restrict__ tte, const int* __restrict__ ttm,
         int eb, int gcnt,
         const int* __restrict__ tok, const float* __restrict__ wgt,
         float* __restrict__ out)
{
    int ty = blockIdx.y;
    if (ty >= *ntile_g) return;
    int e = tte[ty];
    if (e < eb || e >= eb + gcnt) return;
    int m0 = ttm[ty];
    int p1 = expert_off[e + 1];
    int n0 = blockIdx.x * 64;
    __shared__ bf16 As[128 * 64];    // 16 KB
    __shared__ bf16 Bs [64 * 64];    // 8 KB -> 24 KB total
    __shared__ float wgt_s[128];
    __shared__ int   tok_s[128];
    int tid = threadIdx.x, lane = tid & 63, wv = tid >> 6;
    int wm = wv >> 1, wn = wv & 1;
    int l16 = lane & 15, lhi = lane >> 4;
    if (tid < 128) {
        int r = m0 + tid;
        if (r < p1) { wgt_s[tid] = wgt[r]; tok_s[tid] = tok[r]; }
        else        { wgt_s[tid] = 0.f;    tok_s[tid] = 0; }
    }
    f32x4 acc[4][2] = {};

    const bf16* aptr[4]; u32 alds[4];
    #pragma unroll
    for (int c = 0; c < 4; ++c) {
        int g = c * 256 + tid;
        int r = g >> 3, pos = g & 7;
        int gr = m0 + r; if (gr >= p1) gr = p1 - 1;
        int gsrc = pos ^ (r & 7);
        aptr[c] = H1 + (size_t)gr * FFN_ + gsrc * 8;
        alds[c] = g * 16;
    }
    size_t tb0 = (size_t)(e - eb) * EXPELEM + (size_t)(n0 >> 6) * (FFN_ >> 6) * 4096;
    const bf16* bptr[2]; u32 blds[2];
    #pragma unroll
    for (int c = 0; c < 2; ++c) {
        int g = c * 256 + tid;
        bptr[c] = wdT + tb0 + (size_t)g * 8;
        blds[c] = g * 16;
    }
    u32 aro[2][4], bro[2][2];
    #pragma unroll
    for (int ks = 0; ks < 2; ++ks) {
        #pragma unroll
        for (int fm = 0; fm < 4; ++fm) {
            int r = wm * 64 + fm * 16 + l16;
            aro[ks][fm] = r * 128 + ((u32)((ks * 4 + lhi) ^ (r & 7))) * 16;
        }
        #pragma unroll
        for (int fn = 0; fn < 2; ++fn) {
            int fr = wn * 32 + fn * 16 + l16;
            bro[ks][fn] = fr * 128 + ((u32)((ks * 4 + lhi) ^ (fr & 7))) * 16;
        }
    }

    for (int t = 0; t < FFN_ / 64; ++t) {
        #pragma unroll
        for (int c = 0; c < 4; ++c) { gld16(aptr[c], (char*)As + alds[c]); aptr[c] += 64; }
        #pragma unroll
        for (int c = 0; c < 2; ++c) { gld16(bptr[c], (char*)Bs + blds[c]); bptr[c] += 4096; }
        __syncthreads();
        #pragma unroll
        for (int ks = 0; ks < 2; ++ks) {
            bf16x8 af[4];
            #pragma unroll
            for (int fm = 0; fm < 4; ++fm)
                af[fm] = *(const bf16x8*)((char*)As + aro[ks][fm]);
            #pragma unroll
            for (int fn = 0; fn < 2; ++fn) {
                bf16x8 bd = *(const bf16x8*)((char*)Bs + bro[ks][fn]);
                #pragma unroll
                for (int fm = 0; fm < 4; ++fm)
                    acc[fm][fn] = __builtin_amdgcn_mfma_f32_16x16x32_bf16(af[fm], bd, acc[fm][fn], 0, 0, 0);
            }
        }
        __syncthreads();
    }
    #pragma unroll
    for (int fm = 0; fm < 4; ++fm)
    #pragma unroll
    for (int fn = 0; fn < 2; ++fn)
    #pragma unroll
    for (int rg = 0; rg < 4; ++rg) {
        int rl = wm * 64 + fm * 16 + lhi * 4 + rg;
        if (m0 + rl < p1) {
            float v = acc[fm][fn][rg] * wgt_s[rl];
            atomicAdd(out + (size_t)tok_s[rl] * HID + n0 + wn * 32 + fn * 16 + l16, v);
        }
    }
}

extern "C" void kernel_launch(void* const* d_in, const int* in_sizes, int n_in,
                              void* d_out, int out_size, void* d_ws, size_t ws_size,
                              hipStream_t stream)
{
    const float*    x      = (const float*)d_in[0];
    const float*    top_w  = (const float*)d_in[2];
    const uint32_t* te     = (const uint32_t*)d_in[3];
    const float*    w_up   = (const float*)d_in[4];
    const float*    w_gate = (const float*)d_in[5];
    const float*    w_down = (const float*)d_in[6];
    float* out = (float*)d_out;
    char*  ws  = (char*)d_ws;

    int*   expert_off = (int*)(ws + OFF_EXP);
    int*   ntile_g    = (int*)(ws + OFF_NT);
    int*   tte        = (int*)(ws + OFF_TTE);
    int*   ttm        = (int*)(ws + OFF_TTM);
    int*   tok        = (int*)(ws + OFF_TOK);
    float* wgt        = (float*)(ws + OFF_WGT);
    bf16*  Xg         = (bf16*)(ws + OFF_XG);
    bf16*  H1         = (bf16*)(ws + OFF_H1);
    bf16*  WT         = (bf16*)(ws + OFF_WT);

    size_t wtcap = ws_size > (size_t)OFF_WT ? ws_size - (size_t)OFF_WT : 0;
    size_t perexp = EXPELEM * sizeof(bf16);           // 4 MB per expert matrix
    int g1 = (int)(wtcap / (2 * perexp));
    g1 = g1 >= 8 ? 8 : g1 >= 4 ? 4 : g1 >= 2 ? 2 : 1;
    int g2 = (int)(wtcap / perexp);
    g2 = g2 >= 8 ? 8 : g2 >= 4 ? 4 : g2 >= 2 ? 2 : 1;

    hipMemsetAsync(out, 0, (size_t)out_size * sizeof(float), stream);
    hipLaunchKernelGGL(route_kernel, dim3(1), dim3(512), 0, stream,
                       te, top_w, expert_off, ntile_g, tte, ttm, tok, wgt);
    hipLaunchKernelGGL(gather_kernel, dim3(NPAIR), dim3(256), 0, stream,
                       x, tok, Xg);

    for (int eb = 0; eb < NEXP; eb += g1) {
        bf16* wuT = WT;
        bf16* wgT = WT + (size_t)g1 * EXPELEM;
        // R = HID (k-dim), C = FFN (n-dim)
        hipLaunchKernelGGL(transpose_v3, dim3(HID / 64, FFN_ / 64, 2 * g1), dim3(256), 0, stream,
                           w_up + (size_t)eb * EXPELEM, wuT,
                           w_gate + (size_t)eb * EXPELEM, wgT, g1, HID, FFN_);
        hipLaunchKernelGGL(moe_upgate, dim3(FFN_ / 64, MAXTILE), dim3(256), 0, stream,
                           Xg, wuT, wgT, expert_off, ntile_g, tte, ttm, eb, g1, H1);
    }
    for (int eb = 0; eb < NEXP; eb += g2) {
        // R = FFN (k-dim), C = HID (n-dim)
        hipLaunchKernelGGL(transpose_v3, dim3(FFN_ / 64, HID / 64, g2), dim3(256), 0, stream,
                           w_down + (size_t)eb * EXPELEM, WT,
                           w_down + (size_t)eb * EXPELEM, WT, g2, FFN_, HID);
        hipLaunchKernelGGL(moe_down, dim3(HID / 64, MAXTILE), dim3(256), 0, stream,
                           H1, WT, expert_off, ntile_g, tte, ttm, eb, g2, tok, wgt, out);
    }
}